// Round 5
// baseline (495.024 us; speedup 1.0000x reference)
//
#include <hip/hip_runtime.h>
#include <hip/hip_bf16.h>
#include <hip/hip_cooperative_groups.h>

namespace cg = cooperative_groups;

// GNN EdgeConv, 3 layers, fp32 in/out — SINGLE cooperative kernel.
// msg_e = relu(u[src]+w[dst]); u = x@Wa^T (bf16), w = x@(Wb-Wa)^T + b (fp32).
// Edges bucketed by dst (64-slot buckets, no scan) -> gather-max, zero HBM atomics.
// Round-5: round-4 analysis showed ~30-40us of real work vs 145.7us wall ->
// dispatch-boundary-bound. 10 dispatches -> 1 cooperative launch + 6 grid.sync().

#define NODES 4096
#define EDGES 65536
#define OSTR 1024
#define NB 512   // grid blocks (>= 2/CU co-resident: ~64 VGPR, 8.4KB LDS)

typedef __attribute__((ext_vector_type(8))) short bf16x8;
typedef __attribute__((ext_vector_type(4))) float f32x4;

__device__ __forceinline__ unsigned short f2bf(float f) {
    unsigned int x = __float_as_uint(f);
    return (unsigned short)((x + 0x7fff + ((x >> 16) & 1)) >> 16); // RNE
}
__device__ __forceinline__ float bf2f(unsigned short u) {
    return __uint_as_float(((unsigned int)u) << 16);
}

__global__ __launch_bounds__(256, 2) void k_all(
    const float* __restrict__ x0,
    const int* __restrict__ srcIdx,
    const int* __restrict__ dstIdx,
    const float* __restrict__ W0, const float* __restrict__ W1, const float* __restrict__ W2,
    const float* __restrict__ b0, const float* __restrict__ b1, const float* __restrict__ b2,
    float* __restrict__ out,
    unsigned short* __restrict__ UWu,   // [4096][256] bf16
    float* __restrict__ UWw,            // [4096][256] fp32
    unsigned short* __restrict__ xbuf,  // [4096][256] bf16
    short* __restrict__ Wp,             // 3 x [512][256] bf16
    int* __restrict__ cnt,              // [4096] bucket counts
    int* __restrict__ srcS)             // [4096][64] bucketed src ids
{
    cg::grid_group grid = cg::this_grid();
    // stride 264 shorts = 132 dwords == 4 mod 32 -> 2-way LDS conflicts (free, m136)
    __shared__ __align__(16) short Alds[16 * 264];

    const int b = blockIdx.x, t = threadIdx.x;
    const int wave = t >> 6, lane = t & 63;
    const int lm = lane & 15, kq = lane >> 4;

    // ---------- phase 0: setup (x0 copy | W' prep | zero cnt) ----------
    for (int u = b; u < NODES + 1536 + 16; u += NB) {
        if (u < NODES) {
            float v = x0[u * 256 + t];
            out[(size_t)u * OSTR + t] = v;
            xbuf[u * 256 + t] = f2bf(v);
        } else if (u < NODES + 1536) {
            int u2 = u - NODES;
            int layer = u2 >> 9;                      // 512 blocks/layer
            int idx = (u2 & 511) * 256 + t;
            const float* W = layer == 0 ? W0 : (layer == 1 ? W1 : W2);
            int n = idx >> 8, c = idx & 255;
            float v = (n < 256) ? W[n * 512 + c]                               // Wa
                                : W[(n - 256) * 512 + 256 + c] - W[(n - 256) * 512 + c]; // Wb-Wa
            Wp[layer * 131072 + idx] = (short)f2bf(v);
        } else {
            cnt[(u - NODES - 1536) * 256 + t] = 0;
        }
    }
    grid.sync();

    for (int l = 0; l < 3; ++l) {
        const short* WpL = Wp + l * 131072;
        const float* bias = l == 0 ? b0 : (l == 1 ? b1 : b2);

        // ---------- gemm phase: 512 tiles of 16 rows x 256 cols (K=256) ----------
        // l==0 additionally buckets the 65536 edges (units 512..767).
        const int ulim = (l == 0) ? 768 : 512;
        for (int u = b; u < ulim; u += NB) {
            if (u < 512) {
                const int m0 = (u & 255) * 16;
                const int nhalf = u >> 8;
                {   // stage A: 16 rows x 256 k bf16; 16 thr/row x 2 16B-chunks
                    int r = t >> 4, ch = t & 15;
                    const int4* ps = (const int4*)(xbuf + (size_t)(m0 + r) * 256);
                    short* arow = &Alds[r * 264];
                    *(int4*)(arow + ch * 8) = ps[ch];
                    *(int4*)(arow + (ch + 16) * 8) = ps[ch + 16];
                }
                __syncthreads();
                f32x4 acc[4];
#pragma unroll
                for (int nt = 0; nt < 4; ++nt) acc[nt] = (f32x4){0.f, 0.f, 0.f, 0.f};
                // A-frag: A[m=lane&15][k=kq*8+j]; B-frag: B[k][n=lane&15] = Wp row n
                const short* ap = &Alds[lm * 264 + kq * 8];
                const short* bp = WpL + (size_t)(nhalf * 256 + wave * 64 + lm) * 256 + kq * 8;
#pragma unroll
                for (int ks = 0; ks < 8; ++ks) {
                    const int ko = ks * 32;
                    bf16x8 a = *(const bf16x8*)(ap + ko);
                    acc[0] = __builtin_amdgcn_mfma_f32_16x16x32_bf16(a, *(const bf16x8*)(bp + ko), acc[0], 0, 0, 0);
                    acc[1] = __builtin_amdgcn_mfma_f32_16x16x32_bf16(a, *(const bf16x8*)(bp + 4096 + ko), acc[1], 0, 0, 0);
                    acc[2] = __builtin_amdgcn_mfma_f32_16x16x32_bf16(a, *(const bf16x8*)(bp + 8192 + ko), acc[2], 0, 0, 0);
                    acc[3] = __builtin_amdgcn_mfma_f32_16x16x32_bf16(a, *(const bf16x8*)(bp + 12288 + ko), acc[3], 0, 0, 0);
                }
                // C/D: col=lane&15, row=(lane>>4)*4+reg (m89/m91)
#pragma unroll
                for (int nt = 0; nt < 4; ++nt) {
                    int nc = wave * 64 + nt * 16 + lm;
                    float bc = (nhalf == 1) ? bias[nc] : 0.0f;
#pragma unroll
                    for (int p = 0; p < 4; ++p) {
                        int row = kq * 4 + p;
                        float v = acc[nt][p] + bc;
                        size_t off = (size_t)(m0 + row) * 256 + nc;
                        if (nhalf == 0) UWu[off] = f2bf(v);
                        else            UWw[off] = v;
                    }
                }
                __syncthreads();
            } else {
                int e = (u - 512) * 256 + t;
                int d = dstIdx[e];
                int p = atomicAdd(&cnt[d], 1);
                if (p < 64) srcS[d * 64 + p] = srcIdx[e];  // deg~Pois(16), cap 64 safe
            }
        }
        grid.sync();

        // ---------- edge phase: gather-max, 8 nodes/block (1 wave/node) ----------
        const int ooff = (l + 1) * 256;
        for (int i = b * 8 + wave; i < b * 8 + 8; i += 4) {
            const int deg = cnt[i];
            const int base = i * 64;
            const float NEG = -3.4e38f;
            float m0_ = NEG, m1_ = NEG, m2_ = NEG, m3_ = NEG;
            int e = 0;
            for (; e + 4 <= deg; e += 4) {
                int s0 = srcS[base + e], s1 = srcS[base + e + 1];
                int s2 = srcS[base + e + 2], s3 = srcS[base + e + 3];
                ushort4 v0 = *(const ushort4*)(UWu + (size_t)s0 * 256 + lane * 4);
                ushort4 v1 = *(const ushort4*)(UWu + (size_t)s1 * 256 + lane * 4);
                ushort4 v2 = *(const ushort4*)(UWu + (size_t)s2 * 256 + lane * 4);
                ushort4 v3 = *(const ushort4*)(UWu + (size_t)s3 * 256 + lane * 4);
                m0_ = fmaxf(fmaxf(fmaxf(m0_, bf2f(v0.x)), fmaxf(bf2f(v1.x), bf2f(v2.x))), bf2f(v3.x));
                m1_ = fmaxf(fmaxf(fmaxf(m1_, bf2f(v0.y)), fmaxf(bf2f(v1.y), bf2f(v2.y))), bf2f(v3.y));
                m2_ = fmaxf(fmaxf(fmaxf(m2_, bf2f(v0.z)), fmaxf(bf2f(v1.z), bf2f(v2.z))), bf2f(v3.z));
                m3_ = fmaxf(fmaxf(fmaxf(m3_, bf2f(v0.w)), fmaxf(bf2f(v1.w), bf2f(v2.w))), bf2f(v3.w));
            }
            for (; e < deg; ++e) {
                int s = srcS[base + e];
                ushort4 v = *(const ushort4*)(UWu + (size_t)s * 256 + lane * 4);
                m0_ = fmaxf(m0_, bf2f(v.x)); m1_ = fmaxf(m1_, bf2f(v.y));
                m2_ = fmaxf(m2_, bf2f(v.z)); m3_ = fmaxf(m3_, bf2f(v.w));
            }
            float4 w = *(const float4*)(UWw + (size_t)i * 256 + lane * 4);
            float4 r;
            // empty node: NEG + w < 0 -> relu 0 (PyG fill semantics)
            r.x = fmaxf(m0_ + w.x, 0.0f);
            r.y = fmaxf(m1_ + w.y, 0.0f);
            r.z = fmaxf(m2_ + w.z, 0.0f);
            r.w = fmaxf(m3_ + w.w, 0.0f);
            *(float4*)(out + (size_t)i * OSTR + ooff + lane * 4) = r;
            ushort4 rb;
            rb.x = f2bf(r.x); rb.y = f2bf(r.y); rb.z = f2bf(r.z); rb.w = f2bf(r.w);
            *(ushort4*)(xbuf + (size_t)i * 256 + lane * 4) = rb;
        }
        if (l < 2) grid.sync();
    }
}

extern "C" void kernel_launch(void* const* d_in, const int* in_sizes, int n_in,
                              void* d_out, int out_size, void* d_ws, size_t ws_size,
                              hipStream_t stream) {
    const float* x0 = (const float*)d_in[0];
    const int* ei = (const int*)d_in[1];
    const int* srcIdx = ei;          // edge_index[0]
    const int* dstIdx = ei + EDGES;  // edge_index[1]
    const float* W0 = (const float*)d_in[2];
    const float* bb0 = (const float*)d_in[3];
    const float* W1 = (const float*)d_in[4];
    const float* bb1 = (const float*)d_in[5];
    const float* W2 = (const float*)d_in[6];
    const float* bb2 = (const float*)d_in[7];
    float* out = (float*)d_out;

    // ws layout (~10.2 MB; ws is ~268 MB per harness poison size):
    char* w = (char*)d_ws;
    unsigned short* UWu = (unsigned short*)w;                 // 2 MB
    float* UWw = (float*)(w + 2097152);                       // 4 MB
    unsigned short* xbuf = (unsigned short*)(w + 6291456);    // 2 MB
    short* Wp = (short*)(w + 8388608);                        // 768 KB
    int* cnt = (int*)(w + 9175040);                           // 16 KB
    int* srcS = (int*)(w + 9191424);                          // 1 MB

    void* args[] = {&x0, &srcIdx, &dstIdx, &W0, &W1, &W2, &bb0, &bb1, &bb2,
                    &out, &UWu, &UWw, &xbuf, &Wp, &cnt, &srcS};
    hipLaunchCooperativeKernel((const void*)k_all, dim3(NB), dim3(256), args, 0, stream);
}

// Round 6
// 379.213 us; speedup vs baseline: 1.3054x; 1.3054x over previous
//
#include <hip/hip_runtime.h>
#include <hip/hip_bf16.h>
#include <hip/hip_cooperative_groups.h>

// GNN EdgeConv, 3 layers, fp32 in/out — single cooperative kernel with a
// HAND-ROLLED grid barrier (round-5 post-mortem: cg::grid.sync() cost ~60us
// each = 380us of idle; flag+monitor barrier should be ~1-3us each).
// msg_e = relu(u[src]+w[dst]); u = x@Wa^T (bf16), w = x@(Wb-Wa)^T + b (fp32).
// Edges bucketed by dst (64-slot buckets) -> per-node gather-max, no HBM atomics.

#define NODES 4096
#define EDGES 65536
#define OSTR 1024
#define NB 512   // 2 blocks/CU co-resident (48 VGPR, 8.7KB LDS, launch_bounds(256,2))

typedef __attribute__((ext_vector_type(8))) short bf16x8;
typedef __attribute__((ext_vector_type(4))) float f32x4;

__device__ __forceinline__ unsigned short f2bf(float f) {
    unsigned int x = __float_as_uint(f);
    return (unsigned short)((x + 0x7fff + ((x >> 16) & 1)) >> 16); // RNE
}
__device__ __forceinline__ float bf2f(unsigned short u) {
    return __uint_as_float(((unsigned int)u) << 16);
}

// Grid barrier: flags[b*16] (64B stride) hold last epoch block b arrived at;
// block 0 monitors all flags then stores epoch to rel; others spin on rel.
// No init needed: ws poison 0xAA = 0xAAAAAAAA = negative int < epoch>=1.
__device__ __forceinline__ void gbar(int* __restrict__ flags, int* __restrict__ rel,
                                     int epoch) {
    const int b = blockIdx.x, t = threadIdx.x;
    __syncthreads();                       // all phase work done; vmcnt drained
    if (b == 0) {
        int i0 = 2 * t + 1, i1 = 2 * t + 2;   // monitor blocks 1..511
        for (;;) {
            int a = __hip_atomic_load(&flags[i0 * 16], __ATOMIC_RELAXED, __HIP_MEMORY_SCOPE_AGENT);
            int c = (i1 < NB) ? __hip_atomic_load(&flags[i1 * 16], __ATOMIC_RELAXED, __HIP_MEMORY_SCOPE_AGENT) : epoch;
            if (__syncthreads_count((a >= epoch) && (c >= epoch)) == 256) break;
            __builtin_amdgcn_s_sleep(2);
        }
        __threadfence();                   // acquire (inv) + release (wb) for block 0
        if (t == 0)
            __hip_atomic_store(rel, epoch, __ATOMIC_RELEASE, __HIP_MEMORY_SCOPE_AGENT);
        __syncthreads();
    } else {
        if (t == 0) {
            __threadfence();               // make this block's writes device-visible
            __hip_atomic_store(&flags[b * 16], epoch, __ATOMIC_RELEASE, __HIP_MEMORY_SCOPE_AGENT);
            while (__hip_atomic_load(rel, __ATOMIC_RELAXED, __HIP_MEMORY_SCOPE_AGENT) < epoch)
                __builtin_amdgcn_s_sleep(8);
            __threadfence();               // acquire: invalidate local caches
        }
        __syncthreads();
    }
}

__global__ __launch_bounds__(256, 2) void k_all(
    const float* __restrict__ x0,
    const int* __restrict__ srcIdx,
    const int* __restrict__ dstIdx,
    const float* __restrict__ W0, const float* __restrict__ W1, const float* __restrict__ W2,
    const float* __restrict__ b0, const float* __restrict__ b1, const float* __restrict__ b2,
    float* __restrict__ out,
    unsigned short* __restrict__ UWu,   // [4096][256] bf16
    float* __restrict__ UWw,            // [4096][256] fp32
    unsigned short* __restrict__ xbuf,  // [4096][256] bf16
    short* __restrict__ Wp,             // 3 x [512][256] bf16
    int* cnt,                           // [4096] bucket counts (atomics)
    int* __restrict__ srcS,             // [4096][64] bucketed src ids
    int* __restrict__ flags, int* __restrict__ rel)
{
    // stride 264 shorts = 132 dwords == 4 mod 32 -> 2-way LDS conflicts (free, m136)
    __shared__ __align__(16) short Alds[16 * 264];

    const int b = blockIdx.x, t = threadIdx.x;
    const int wave = t >> 6, lane = t & 63;
    const int lm = lane & 15, kq = lane >> 4;
    int epoch = 0;

    // ---------- phase 0: setup (x0 copy | W' prep | zero cnt) ----------
    for (int u = b; u < NODES + 1536 + 16; u += NB) {
        if (u < NODES) {
            float v = x0[u * 256 + t];
            out[(size_t)u * OSTR + t] = v;
            xbuf[u * 256 + t] = f2bf(v);
        } else if (u < NODES + 1536) {
            int u2 = u - NODES;
            int layer = u2 >> 9;
            int idx = (u2 & 511) * 256 + t;
            const float* W = layer == 0 ? W0 : (layer == 1 ? W1 : W2);
            int n = idx >> 8, c = idx & 255;
            float v = (n < 256) ? W[n * 512 + c]
                                : W[(n - 256) * 512 + 256 + c] - W[(n - 256) * 512 + c];
            Wp[layer * 131072 + idx] = (short)f2bf(v);
        } else {
            cnt[(u - NODES - 1536) * 256 + t] = 0;
        }
    }
    gbar(flags, rel, ++epoch);

    for (int l = 0; l < 3; ++l) {
        const short* WpL = Wp + l * 131072;
        const float* bias = l == 0 ? b0 : (l == 1 ? b1 : b2);

        // ---------- gemm: 512 tiles (16 rows x 256 cols, K=256); l==0 adds scatter ----------
        const int ulim = (l == 0) ? 768 : 512;
        for (int u = b; u < ulim; u += NB) {
            if (u < 512) {
                const int m0 = (u & 255) * 16;
                const int nhalf = u >> 8;
                {   // stage A: 16 rows x 256 k bf16; 16 thr/row x 2 16B-chunks
                    int r = t >> 4, ch = t & 15;
                    const int4* ps = (const int4*)(xbuf + (size_t)(m0 + r) * 256);
                    short* arow = &Alds[r * 264];
                    *(int4*)(arow + ch * 8) = ps[ch];
                    *(int4*)(arow + (ch + 16) * 8) = ps[ch + 16];
                }
                __syncthreads();
                f32x4 acc[4];
#pragma unroll
                for (int nt = 0; nt < 4; ++nt) acc[nt] = (f32x4){0.f, 0.f, 0.f, 0.f};
                const short* ap = &Alds[lm * 264 + kq * 8];
                const short* bp = WpL + (size_t)(nhalf * 256 + wave * 64 + lm) * 256 + kq * 8;
#pragma unroll
                for (int ks = 0; ks < 8; ++ks) {
                    const int ko = ks * 32;
                    bf16x8 a = *(const bf16x8*)(ap + ko);
                    acc[0] = __builtin_amdgcn_mfma_f32_16x16x32_bf16(a, *(const bf16x8*)(bp + ko), acc[0], 0, 0, 0);
                    acc[1] = __builtin_amdgcn_mfma_f32_16x16x32_bf16(a, *(const bf16x8*)(bp + 4096 + ko), acc[1], 0, 0, 0);
                    acc[2] = __builtin_amdgcn_mfma_f32_16x16x32_bf16(a, *(const bf16x8*)(bp + 8192 + ko), acc[2], 0, 0, 0);
                    acc[3] = __builtin_amdgcn_mfma_f32_16x16x32_bf16(a, *(const bf16x8*)(bp + 12288 + ko), acc[3], 0, 0, 0);
                }
                // C/D: col=lane&15, row=(lane>>4)*4+reg (m89/m91)
#pragma unroll
                for (int nt = 0; nt < 4; ++nt) {
                    int nc = wave * 64 + nt * 16 + lm;
                    float bc = (nhalf == 1) ? bias[nc] : 0.0f;
#pragma unroll
                    for (int p = 0; p < 4; ++p) {
                        int row = kq * 4 + p;
                        float v = acc[nt][p] + bc;
                        size_t off = (size_t)(m0 + row) * 256 + nc;
                        if (nhalf == 0) UWu[off] = f2bf(v);
                        else            UWw[off] = v;
                    }
                }
                __syncthreads();
            } else {
                int e = (u - 512) * 256 + t;
                int d = dstIdx[e];
                int p = atomicAdd(&cnt[d], 1);
                if (p < 64) srcS[d * 64 + p] = srcIdx[e];  // deg~Pois(16); cap 64 safe
            }
        }
        gbar(flags, rel, ++epoch);

        // ---------- edge: gather-max, 8 nodes/block, 1 wave/node ----------
        const int ooff = (l + 1) * 256;
        for (int i = b * 8 + wave; i < b * 8 + 8; i += 4) {
            // atomic load: bypasses scalar/L1 caches (cnt written by other XCDs)
            const int deg = __hip_atomic_load(&cnt[i], __ATOMIC_RELAXED, __HIP_MEMORY_SCOPE_AGENT);
            const int base = i * 64;
            const float NEG = -3.4e38f;
            float m0_ = NEG, m1_ = NEG, m2_ = NEG, m3_ = NEG;
            // chunks of 4 with clamp; duplicates are harmless under max.
            // per-lane srcS load + shfl broadcast: forces vector loads (no stale
            // scalar-cache reads of data written by other XCDs this launch).
            for (int e = 0; e < deg; e += 4) {
                int idx = e + (lane & 3);
                if (idx >= deg) idx = deg - 1;
                int sv = srcS[base + idx];
                int s0 = __shfl(sv, 0), s1 = __shfl(sv, 1);
                int s2 = __shfl(sv, 2), s3 = __shfl(sv, 3);
                ushort4 v0 = *(const ushort4*)(UWu + (size_t)s0 * 256 + lane * 4);
                ushort4 v1 = *(const ushort4*)(UWu + (size_t)s1 * 256 + lane * 4);
                ushort4 v2 = *(const ushort4*)(UWu + (size_t)s2 * 256 + lane * 4);
                ushort4 v3 = *(const ushort4*)(UWu + (size_t)s3 * 256 + lane * 4);
                m0_ = fmaxf(fmaxf(fmaxf(m0_, bf2f(v0.x)), fmaxf(bf2f(v1.x), bf2f(v2.x))), bf2f(v3.x));
                m1_ = fmaxf(fmaxf(fmaxf(m1_, bf2f(v0.y)), fmaxf(bf2f(v1.y), bf2f(v2.y))), bf2f(v3.y));
                m2_ = fmaxf(fmaxf(fmaxf(m2_, bf2f(v0.z)), fmaxf(bf2f(v1.z), bf2f(v2.z))), bf2f(v3.z));
                m3_ = fmaxf(fmaxf(fmaxf(m3_, bf2f(v0.w)), fmaxf(bf2f(v1.w), bf2f(v2.w))), bf2f(v3.w));
            }
            float4 w = *(const float4*)(UWw + (size_t)i * 256 + lane * 4);
            float4 r;
            // empty node: NEG + w < 0 -> relu 0 (PyG fill semantics)
            r.x = fmaxf(m0_ + w.x, 0.0f);
            r.y = fmaxf(m1_ + w.y, 0.0f);
            r.z = fmaxf(m2_ + w.z, 0.0f);
            r.w = fmaxf(m3_ + w.w, 0.0f);
            *(float4*)(out + (size_t)i * OSTR + ooff + lane * 4) = r;
            ushort4 rb;
            rb.x = f2bf(r.x); rb.y = f2bf(r.y); rb.z = f2bf(r.z); rb.w = f2bf(r.w);
            *(ushort4*)(xbuf + (size_t)i * 256 + lane * 4) = rb;
        }
        if (l < 2) gbar(flags, rel, ++epoch);
    }
}

extern "C" void kernel_launch(void* const* d_in, const int* in_sizes, int n_in,
                              void* d_out, int out_size, void* d_ws, size_t ws_size,
                              hipStream_t stream) {
    const float* x0 = (const float*)d_in[0];
    const int* ei = (const int*)d_in[1];
    const int* srcIdx = ei;          // edge_index[0]
    const int* dstIdx = ei + EDGES;  // edge_index[1]
    const float* W0 = (const float*)d_in[2];
    const float* bb0 = (const float*)d_in[3];
    const float* W1 = (const float*)d_in[4];
    const float* bb1 = (const float*)d_in[5];
    const float* W2 = (const float*)d_in[6];
    const float* bb2 = (const float*)d_in[7];
    float* out = (float*)d_out;

    // ws layout (~10.3 MB):
    char* w = (char*)d_ws;
    unsigned short* UWu = (unsigned short*)w;                 // 2 MB
    float* UWw = (float*)(w + 2097152);                       // 4 MB
    unsigned short* xbuf = (unsigned short*)(w + 6291456);    // 2 MB
    short* Wp = (short*)(w + 8388608);                        // 768 KB
    int* cnt = (int*)(w + 9175040);                           // 16 KB
    int* srcS = (int*)(w + 9191424);                          // 1 MB
    int* flags = (int*)(w + 10240000);                        // 32 KB (64B-strided)
    int* rel = (int*)(w + 10272768);                          // 64 B

    void* args[] = {&x0, &srcIdx, &dstIdx, &W0, &W1, &W2, &bb0, &bb1, &bb2,
                    &out, &UWu, &UWw, &xbuf, &Wp, &cnt, &srcS, &flags, &rel};
    hipLaunchCooperativeKernel((const void*)k_all, dim3(NB), dim3(256), args, 0, stream);
}

// Round 7
// 170.116 us; speedup vs baseline: 2.9099x; 2.2291x over previous
//
#include <hip/hip_runtime.h>
#include <hip/hip_bf16.h>

// GNN EdgeConv, 3 layers, fp32 in/out. 5 dispatches:
//   k_setup : x0->out cols[0,256), W'=[Wa|Wb-Wa] bf16 prep, zero cnt
//   k_g0    : gemm0 (u=x0@Wa^T bf16, w=x0@(Wb-Wa)^T+b fp32) + edge bucketing
//   k_fuse  : edge-max(layer l) -> out + LDS A-tile -> gemm(l+1)   [x2]
//   k_last  : edge-max(layer 2) -> out
// Round-7 rationale: in-kernel grid barriers cost 20-40us each on MI355X
// (8 non-coherent XCD L2s force wb/inv per fence; rounds 5/6 measured 250-380us
// idle). Dispatch boundaries are ~3us. GEMM A-tiles are row-local, so
// edge(l)+gemm(l+1) fuse into one block via LDS. UW tables ping-pong (other
// blocks still read layer-l rows while this block writes layer-l+1).

#define NODES 4096
#define EDGES 65536
#define OSTR 1024

typedef __attribute__((ext_vector_type(8))) short bf16x8;
typedef __attribute__((ext_vector_type(4))) float f32x4;

__device__ __forceinline__ unsigned short f2bf(float f) {
    unsigned int x = __float_as_uint(f);
    return (unsigned short)((x + 0x7fff + ((x >> 16) & 1)) >> 16); // RNE
}
__device__ __forceinline__ float bf2f(unsigned short u) {
    return __uint_as_float(((unsigned int)u) << 16);
}

// ---------------- D1: setup ----------------
__global__ __launch_bounds__(256) void k_setup(const float* __restrict__ x0,
                                               float* __restrict__ out,
                                               const float* __restrict__ W0,
                                               const float* __restrict__ W1,
                                               const float* __restrict__ W2,
                                               short* __restrict__ Wp,
                                               int* __restrict__ cnt) {
    int b = blockIdx.x, t = threadIdx.x;
    if (b < NODES) {
        out[(size_t)b * OSTR + t] = x0[b * 256 + t];
    } else if (b < NODES + 1536) {
        int b2 = b - NODES;
        int layer = b2 >> 9;                    // 512 blocks/layer
        int idx = (b2 & 511) * 256 + t;
        const float* W = layer == 0 ? W0 : (layer == 1 ? W1 : W2);
        int n = idx >> 8, c = idx & 255;
        float v = (n < 256) ? W[n * 512 + c]                                     // Wa
                            : W[(n - 256) * 512 + 256 + c] - W[(n - 256) * 512 + c]; // Wb-Wa
        Wp[layer * 131072 + idx] = (short)f2bf(v);
    } else {
        cnt[(b - NODES - 1536) * 256 + t] = 0;
    }
}

// shared GEMM core: A-tile (16 rows x 256 k bf16) in Alds; 4 waves x 128 cols.
// writes UWu (cols 0..255, bf16) / UWw (cols 256..511 - 256, fp32, +bias).
__device__ __forceinline__ void gemm16(const short* __restrict__ Alds,
                                       const short* __restrict__ WpL,
                                       const float* __restrict__ bias,
                                       unsigned short* __restrict__ UWuOut,
                                       float* __restrict__ UWwOut,
                                       int n0, int wave, int lane) {
    const int lm = lane & 15, kq = lane >> 4;
    f32x4 acc[8];
#pragma unroll
    for (int nt = 0; nt < 8; ++nt) acc[nt] = (f32x4){0.f, 0.f, 0.f, 0.f};
    // A-frag: A[m=lane&15][k=kq*8+j]; B-frag: B[k][n=lane&15] = Wp row n
    const short* ap = Alds + lm * 264 + kq * 8;
    const short* bp = WpL + (size_t)(wave * 128 + lm) * 256 + kq * 8;
#pragma unroll
    for (int ks = 0; ks < 8; ++ks) {
        const int ko = ks * 32;
        bf16x8 a = *(const bf16x8*)(ap + ko);
#pragma unroll
        for (int nt = 0; nt < 8; ++nt)
            acc[nt] = __builtin_amdgcn_mfma_f32_16x16x32_bf16(
                a, *(const bf16x8*)(bp + nt * 16 * 256 + ko), acc[nt], 0, 0, 0);
    }
    // C/D: col=lane&15, row=(lane>>4)*4+reg (m89/m91-verified)
#pragma unroll
    for (int nt = 0; nt < 8; ++nt) {
        int nc = wave * 128 + nt * 16 + lm;     // 0..511
#pragma unroll
        for (int p = 0; p < 4; ++p) {
            int row = kq * 4 + p;
            float v = acc[nt][p];
            size_t off = (size_t)(n0 + row) * 256;
            if (nc < 256) UWuOut[off + nc] = f2bf(v);
            else          UWwOut[off + nc - 256] = v + bias[nc - 256];
        }
    }
}

// ---------------- D2: gemm0 (blocks 0..255) + bucketing (256..511) ----------------
__global__ __launch_bounds__(256) void k_g0(const float* __restrict__ x0,
                                            const short* __restrict__ WpL,
                                            const float* __restrict__ bias,
                                            unsigned short* __restrict__ UWuOut,
                                            float* __restrict__ UWwOut,
                                            const int* __restrict__ srcIdx,
                                            const int* __restrict__ dstIdx,
                                            int* cnt,
                                            int* __restrict__ srcS) {
    // stride 264 shorts = 132 dwords == 4 mod 32 -> 2-way LDS conflicts (free, m136)
    __shared__ __align__(16) short Alds[16 * 264];
    const int t = threadIdx.x;
    if (blockIdx.x < 256) {
        const int n0 = blockIdx.x * 16;
        {   // stage A: 16 rows x 256 fp32 -> bf16; 16 thr/row x 16 floats
            int r = t >> 4, ci = t & 15;
            const float4* xr = (const float4*)(x0 + (size_t)(n0 + r) * 256);
            float4 f0 = xr[ci * 4], f1 = xr[ci * 4 + 1];
            float4 f2 = xr[ci * 4 + 2], f3 = xr[ci * 4 + 3];
            int4 p0, p1;
            unsigned short* u0 = (unsigned short*)&p0;
            unsigned short* u1 = (unsigned short*)&p1;
            u0[0] = f2bf(f0.x); u0[1] = f2bf(f0.y); u0[2] = f2bf(f0.z); u0[3] = f2bf(f0.w);
            u0[4] = f2bf(f1.x); u0[5] = f2bf(f1.y); u0[6] = f2bf(f1.z); u0[7] = f2bf(f1.w);
            u1[0] = f2bf(f2.x); u1[1] = f2bf(f2.y); u1[2] = f2bf(f2.z); u1[3] = f2bf(f2.w);
            u1[4] = f2bf(f3.x); u1[5] = f2bf(f3.y); u1[6] = f2bf(f3.z); u1[7] = f2bf(f3.w);
            *(int4*)(&Alds[r * 264 + ci * 16]) = p0;
            *(int4*)(&Alds[r * 264 + ci * 16 + 8]) = p1;
        }
        __syncthreads();
        gemm16(Alds, WpL, bias, UWuOut, UWwOut, n0, t >> 6, t & 63);
    } else {
        int e = (blockIdx.x - 256) * 256 + t;
        int d = dstIdx[e];
        int p = atomicAdd(&cnt[d], 1);
        if (p < 64) srcS[d * 64 + p] = srcIdx[e];  // deg~Pois(16); cap never hit (r5/r6)
    }
}

// shared edge-max: node i, one wave; returns relu(max u[src]+w[i]) as float4.
__device__ __forceinline__ float4 edge_max(const unsigned short* __restrict__ UWuIn,
                                           const float* __restrict__ UWwIn,
                                           const int* __restrict__ cnt,
                                           const int* __restrict__ srcS,
                                           int i, int lane) {
    int deg = cnt[i]; deg = deg > 64 ? 64 : deg;
    const int base = i * 64;
    const float NEG = -3.4e38f;
    float m0 = NEG, m1 = NEG, m2 = NEG, m3 = NEG;
    int e = 0;
    for (; e + 4 <= deg; e += 4) {
        int s0 = srcS[base + e],     s1 = srcS[base + e + 1];
        int s2 = srcS[base + e + 2], s3 = srcS[base + e + 3];
        ushort4 v0 = *(const ushort4*)(UWuIn + (size_t)s0 * 256 + lane * 4);
        ushort4 v1 = *(const ushort4*)(UWuIn + (size_t)s1 * 256 + lane * 4);
        ushort4 v2 = *(const ushort4*)(UWuIn + (size_t)s2 * 256 + lane * 4);
        ushort4 v3 = *(const ushort4*)(UWuIn + (size_t)s3 * 256 + lane * 4);
        m0 = fmaxf(fmaxf(fmaxf(m0, bf2f(v0.x)), fmaxf(bf2f(v1.x), bf2f(v2.x))), bf2f(v3.x));
        m1 = fmaxf(fmaxf(fmaxf(m1, bf2f(v0.y)), fmaxf(bf2f(v1.y), bf2f(v2.y))), bf2f(v3.y));
        m2 = fmaxf(fmaxf(fmaxf(m2, bf2f(v0.z)), fmaxf(bf2f(v1.z), bf2f(v2.z))), bf2f(v3.z));
        m3 = fmaxf(fmaxf(fmaxf(m3, bf2f(v0.w)), fmaxf(bf2f(v1.w), bf2f(v2.w))), bf2f(v3.w));
    }
    for (; e < deg; ++e) {
        int s = srcS[base + e];
        ushort4 v = *(const ushort4*)(UWuIn + (size_t)s * 256 + lane * 4);
        m0 = fmaxf(m0, bf2f(v.x)); m1 = fmaxf(m1, bf2f(v.y));
        m2 = fmaxf(m2, bf2f(v.z)); m3 = fmaxf(m3, bf2f(v.w));
    }
    float4 w = *(const float4*)(UWwIn + (size_t)i * 256 + lane * 4);
    float4 r;
    // empty node: NEG + w < 0 -> relu 0 (PyG fill semantics)
    r.x = fmaxf(m0 + w.x, 0.0f);
    r.y = fmaxf(m1 + w.y, 0.0f);
    r.z = fmaxf(m2 + w.z, 0.0f);
    r.w = fmaxf(m3 + w.w, 0.0f);
    return r;
}

// ---------------- D3/D4: edge(l) -> out + A-tile -> gemm(l+1) ----------------
__global__ __launch_bounds__(256) void k_fuse(const unsigned short* __restrict__ UWuIn,
                                              const float* __restrict__ UWwIn,
                                              unsigned short* __restrict__ UWuOut,
                                              float* __restrict__ UWwOut,
                                              const int* __restrict__ cnt,
                                              const int* __restrict__ srcS,
                                              const short* __restrict__ WpL,
                                              const float* __restrict__ bias,
                                              float* __restrict__ out, int ooff) {
    __shared__ __align__(16) short Alds[16 * 264];
    const int t = threadIdx.x, wave = t >> 6, lane = t & 63;
    const int n0 = blockIdx.x * 16;

    // edge phase: 4 nodes per wave
#pragma unroll
    for (int j = 0; j < 4; ++j) {
        const int r = wave * 4 + j;
        const int i = n0 + r;
        float4 rr = edge_max(UWuIn, UWwIn, cnt, srcS, i, lane);
        *(float4*)(out + (size_t)i * OSTR + ooff + lane * 4) = rr;
        ushort4 rb;
        rb.x = f2bf(rr.x); rb.y = f2bf(rr.y); rb.z = f2bf(rr.z); rb.w = f2bf(rr.w);
        *(ushort4*)(&Alds[r * 264 + lane * 4]) = rb;   // row-local A-tile handoff
    }
    __syncthreads();
    gemm16(Alds, WpL, bias, UWuOut, UWwOut, n0, wave, lane);
}

// ---------------- D5: final edge-max ----------------
__global__ __launch_bounds__(256) void k_last(const unsigned short* __restrict__ UWuIn,
                                              const float* __restrict__ UWwIn,
                                              const int* __restrict__ cnt,
                                              const int* __restrict__ srcS,
                                              float* __restrict__ out, int ooff) {
    const int t = threadIdx.x, wave = t >> 6, lane = t & 63;
    const int n0 = blockIdx.x * 16;
#pragma unroll
    for (int j = 0; j < 4; ++j) {
        const int i = n0 + wave * 4 + j;
        float4 rr = edge_max(UWuIn, UWwIn, cnt, srcS, i, lane);
        *(float4*)(out + (size_t)i * OSTR + ooff + lane * 4) = rr;
    }
}

extern "C" void kernel_launch(void* const* d_in, const int* in_sizes, int n_in,
                              void* d_out, int out_size, void* d_ws, size_t ws_size,
                              hipStream_t stream) {
    const float* x0 = (const float*)d_in[0];
    const int* ei = (const int*)d_in[1];
    const int* srcIdx = ei;          // edge_index[0]
    const int* dstIdx = ei + EDGES;  // edge_index[1]
    float* out = (float*)d_out;

    // ws layout (~13.8 MB): UWuA 2M | UWwA 4M | UWuB 2M | UWwB 4M | Wp 768K | cnt 16K | srcS 1M
    char* w = (char*)d_ws;
    unsigned short* UWuA = (unsigned short*)w;
    float*          UWwA = (float*)(w + 2097152);
    unsigned short* UWuB = (unsigned short*)(w + 6291456);
    float*          UWwB = (float*)(w + 8388608);
    short*          Wp   = (short*)(w + 12582912);
    int*            cnt  = (int*)(w + 13369344);
    int*            srcS = (int*)(w + 13385728);

    k_setup<<<NODES + 1536 + 16, 256, 0, stream>>>(x0, out,
        (const float*)d_in[2], (const float*)d_in[4], (const float*)d_in[6], Wp, cnt);
    k_g0<<<512, 256, 0, stream>>>(x0, Wp, (const float*)d_in[3], UWuA, UWwA,
                                  srcIdx, dstIdx, cnt, srcS);
    k_fuse<<<256, 256, 0, stream>>>(UWuA, UWwA, UWuB, UWwB, cnt, srcS,
                                    Wp + 131072, (const float*)d_in[5], out, 256);
    k_fuse<<<256, 256, 0, stream>>>(UWuB, UWwB, UWuA, UWwA, cnt, srcS,
                                    Wp + 262144, (const float*)d_in[7], out, 512);
    k_last<<<256, 256, 0, stream>>>(UWuA, UWwA, cnt, srcS, out, 768);
}

// Round 8
// 163.600 us; speedup vs baseline: 3.0258x; 1.0398x over previous
//
#include <hip/hip_runtime.h>
#include <hip/hip_bf16.h>

// GNN EdgeConv, 3 layers, fp32 in/out. 5 dispatches:
//   k_setup : Wp0 = [Wa|Wb-Wa] bf16 prep + zero cnt                  (528 blocks)
//   k_g0    : gemm0 (u,w from x0; also copies x0->out) + edge bucket + Wp1/Wp2 prep
//   k_fuse  : edge-max(l) [ILP-interleaved] -> out + LDS -> gemm(l+1)  [x2]
//   k_last  : edge-max(2) -> out, 1024 blocks / 1 node per wave (TLP)
// r7 post-mortem: fused edge phase lost TLP (1 blk/CU, 4 seq nodes/wave) ->
// +24us. Fix: interleave the wave's 4 nodes into ONE gather loop (16
// outstanding loads/iter, ~6 iters vs 16) = ILP replaces TLP; k_last back to
// 1024 blocks. msg_e = relu(u[src]+w[dst]); u=x@Wa^T bf16, w=x@(Wb-Wa)^T+b fp32.

#define NODES 4096
#define EDGES 65536
#define OSTR 1024

typedef __attribute__((ext_vector_type(8))) short bf16x8;
typedef __attribute__((ext_vector_type(4))) float f32x4;

__device__ __forceinline__ unsigned short f2bf(float f) {
    unsigned int x = __float_as_uint(f);
    return (unsigned short)((x + 0x7fff + ((x >> 16) & 1)) >> 16); // RNE
}
__device__ __forceinline__ float bf2f(unsigned short u) {
    return __uint_as_float(((unsigned int)u) << 16);
}

__device__ __forceinline__ void wprep_unit(const float* __restrict__ W,
                                           short* __restrict__ WpL,
                                           int idx) {
    int n = idx >> 8, c = idx & 255;
    float v = (n < 256) ? W[n * 512 + c]                                     // Wa
                        : W[(n - 256) * 512 + 256 + c] - W[(n - 256) * 512 + c]; // Wb-Wa
    WpL[idx] = (short)f2bf(v);
}

// ---------------- D1: Wp0 prep + zero cnt ----------------
__global__ __launch_bounds__(256) void k_setup(const float* __restrict__ W0,
                                               short* __restrict__ Wp,
                                               int* __restrict__ cnt) {
    int b = blockIdx.x, t = threadIdx.x;
    if (b < 512) wprep_unit(W0, Wp, b * 256 + t);
    else         cnt[(b - 512) * 256 + t] = 0;
}

// shared GEMM core: A-tile (16 rows x 256 k bf16, stride 264) in Alds;
// 4 waves x 128 cols. UWu = cols[0,256) bf16; UWw = cols[256,512)+bias fp32.
__device__ __forceinline__ void gemm16(const short* __restrict__ Alds,
                                       const short* __restrict__ WpL,
                                       const float* __restrict__ bias,
                                       unsigned short* __restrict__ UWuOut,
                                       float* __restrict__ UWwOut,
                                       int n0, int wave, int lane) {
    const int lm = lane & 15, kq = lane >> 4;
    f32x4 acc[8];
#pragma unroll
    for (int nt = 0; nt < 8; ++nt) acc[nt] = (f32x4){0.f, 0.f, 0.f, 0.f};
    // A-frag: A[m=lane&15][k=kq*8+j]; B-frag: B[k][n=lane&15] = Wp row n
    const short* ap = Alds + lm * 264 + kq * 8;
    const short* bp = WpL + (size_t)(wave * 128 + lm) * 256 + kq * 8;
#pragma unroll
    for (int ks = 0; ks < 8; ++ks) {
        const int ko = ks * 32;
        bf16x8 a = *(const bf16x8*)(ap + ko);
#pragma unroll
        for (int nt = 0; nt < 8; ++nt)
            acc[nt] = __builtin_amdgcn_mfma_f32_16x16x32_bf16(
                a, *(const bf16x8*)(bp + nt * 16 * 256 + ko), acc[nt], 0, 0, 0);
    }
    // C/D: col=lane&15, row=(lane>>4)*4+reg (m89/m91-verified)
#pragma unroll
    for (int nt = 0; nt < 8; ++nt) {
        int nc = wave * 128 + nt * 16 + lm;     // 0..511
#pragma unroll
        for (int p = 0; p < 4; ++p) {
            int row = kq * 4 + p;
            float v = acc[nt][p];
            size_t off = (size_t)(n0 + row) * 256;
            if (nc < 256) UWuOut[off + nc] = f2bf(v);
            else          UWwOut[off + nc - 256] = v + bias[nc - 256];
        }
    }
}

// ---------------- D2: gemm0 + x0->out copy | bucketing | Wp1/Wp2 prep ----------------
__global__ __launch_bounds__(256) void k_g0(const float* __restrict__ x0,
                                            const short* __restrict__ Wp,
                                            const float* __restrict__ bias,
                                            unsigned short* __restrict__ UWuOut,
                                            float* __restrict__ UWwOut,
                                            const int* __restrict__ srcIdx,
                                            const int* __restrict__ dstIdx,
                                            int* cnt,
                                            int* __restrict__ srcS,
                                            const float* __restrict__ W1,
                                            const float* __restrict__ W2,
                                            float* __restrict__ out) {
    // stride 264 shorts = 132 dwords == 4 mod 32 -> 2-way LDS conflicts (free, m136)
    __shared__ __align__(16) short Alds[16 * 264];
    const int b = blockIdx.x, t = threadIdx.x;
    if (b < 256) {
        const int n0 = b * 16;
        {   // stage A: 16 rows x 256 fp32 -> bf16; also the x0->out fp32 copy
            int r = t >> 4, ci = t & 15;
            const float4* xr = (const float4*)(x0 + (size_t)(n0 + r) * 256);
            float4 f[4];
            f[0] = xr[ci * 4]; f[1] = xr[ci * 4 + 1];
            f[2] = xr[ci * 4 + 2]; f[3] = xr[ci * 4 + 3];
            float4* orow = (float4*)(out + (size_t)(n0 + r) * OSTR);
#pragma unroll
            for (int q = 0; q < 4; ++q) orow[ci * 4 + q] = f[q];
            int4 p0, p1;
            unsigned short* u0 = (unsigned short*)&p0;
            unsigned short* u1 = (unsigned short*)&p1;
#pragma unroll
            for (int q = 0; q < 2; ++q) {
                unsigned short* uu = q ? u1 : u0;
                uu[0] = f2bf(f[2*q].x); uu[1] = f2bf(f[2*q].y);
                uu[2] = f2bf(f[2*q].z); uu[3] = f2bf(f[2*q].w);
                uu[4] = f2bf(f[2*q+1].x); uu[5] = f2bf(f[2*q+1].y);
                uu[6] = f2bf(f[2*q+1].z); uu[7] = f2bf(f[2*q+1].w);
            }
            *(int4*)(&Alds[r * 264 + ci * 16]) = p0;
            *(int4*)(&Alds[r * 264 + ci * 16 + 8]) = p1;
        }
        __syncthreads();
        gemm16(Alds, Wp, bias, UWuOut, UWwOut, n0, t >> 6, t & 63);
    } else if (b < 512) {
        int e = (b - 256) * 256 + t;
        int d = dstIdx[e];
        int p = atomicAdd(&cnt[d], 1);
        if (p < 64) srcS[d * 64 + p] = srcIdx[e];  // deg~Pois(16); cap never hit
    } else {
        int b2 = b - 512;                          // 0..1023: Wp1 then Wp2
        const float* W = (b2 < 512) ? W1 : W2;
        short* WpL = (short*)Wp + ((b2 < 512) ? 131072 : 262144);
        wprep_unit(W, WpL, (b2 & 511) * 256 + t);
    }
}

// ---- ILP edge-max: one wave, 4 nodes interleaved in a single gather loop ----
__device__ __forceinline__ void edge4_ilp(const unsigned short* __restrict__ UWu,
                                          const float* __restrict__ UWw,
                                          const int* __restrict__ cnt,
                                          const int* __restrict__ srcS,
                                          int ibase, int lane, float4* res) {
    int dg[4], bs[4]; bool emp[4]; int mx = 1;
#pragma unroll
    for (int j = 0; j < 4; ++j) {
        int d = cnt[ibase + j];
        d = d > 64 ? 64 : d;
        emp[j] = (d <= 0);
        dg[j] = emp[j] ? 1 : d;
        bs[j] = (ibase + j) * 64;
        mx = dg[j] > mx ? dg[j] : mx;
    }
    const float NEG = -3.4e38f;
    float m0[4], m1[4], m2[4], m3[4];
#pragma unroll
    for (int j = 0; j < 4; ++j) { m0[j] = NEG; m1[j] = NEG; m2[j] = NEG; m3[j] = NEG; }
    for (int e = 0; e < mx; e += 4) {
        int s[4][4];
#pragma unroll
        for (int j = 0; j < 4; ++j) {
            int dm1 = dg[j] - 1;
#pragma unroll
            for (int k = 0; k < 4; ++k) {
                int idx = e + k; idx = idx > dm1 ? dm1 : idx;   // dup-clamp (max-safe)
                s[j][k] = emp[j] ? 0 : srcS[bs[j] + idx];       // never reads poison
            }
        }
        ushort4 v[4][4];
#pragma unroll
        for (int j = 0; j < 4; ++j)
#pragma unroll
            for (int k = 0; k < 4; ++k)
                v[j][k] = *(const ushort4*)(UWu + (size_t)s[j][k] * 256 + lane * 4);
#pragma unroll
        for (int j = 0; j < 4; ++j)
#pragma unroll
            for (int k = 0; k < 4; ++k) {
                m0[j] = fmaxf(m0[j], bf2f(v[j][k].x));
                m1[j] = fmaxf(m1[j], bf2f(v[j][k].y));
                m2[j] = fmaxf(m2[j], bf2f(v[j][k].z));
                m3[j] = fmaxf(m3[j], bf2f(v[j][k].w));
            }
    }
#pragma unroll
    for (int j = 0; j < 4; ++j) {
        float4 w = *(const float4*)(UWw + (size_t)(ibase + j) * 256 + lane * 4);
        float a0 = emp[j] ? NEG : m0[j], a1 = emp[j] ? NEG : m1[j];
        float a2 = emp[j] ? NEG : m2[j], a3 = emp[j] ? NEG : m3[j];
        // empty node: NEG + w < 0 -> relu 0 (PyG fill semantics)
        res[j].x = fmaxf(a0 + w.x, 0.0f);
        res[j].y = fmaxf(a1 + w.y, 0.0f);
        res[j].z = fmaxf(a2 + w.z, 0.0f);
        res[j].w = fmaxf(a3 + w.w, 0.0f);
    }
}

// ---------------- D3/D4: edge(l) -> out + A-tile -> gemm(l+1) ----------------
__global__ __launch_bounds__(256) void k_fuse(const unsigned short* __restrict__ UWuIn,
                                              const float* __restrict__ UWwIn,
                                              unsigned short* __restrict__ UWuOut,
                                              float* __restrict__ UWwOut,
                                              const int* __restrict__ cnt,
                                              const int* __restrict__ srcS,
                                              const short* __restrict__ WpL,
                                              const float* __restrict__ bias,
                                              float* __restrict__ out, int ooff) {
    __shared__ __align__(16) short Alds[16 * 264];
    const int t = threadIdx.x, wave = t >> 6, lane = t & 63;
    const int n0 = blockIdx.x * 16;

    float4 res[4];
    edge4_ilp(UWuIn, UWwIn, cnt, srcS, n0 + wave * 4, lane, res);
#pragma unroll
    for (int j = 0; j < 4; ++j) {
        const int r = wave * 4 + j;
        *(float4*)(out + (size_t)(n0 + r) * OSTR + ooff + lane * 4) = res[j];
        ushort4 rb;
        rb.x = f2bf(res[j].x); rb.y = f2bf(res[j].y);
        rb.z = f2bf(res[j].z); rb.w = f2bf(res[j].w);
        *(ushort4*)(&Alds[r * 264 + lane * 4]) = rb;   // row-local A-tile handoff
    }
    __syncthreads();
    gemm16(Alds, WpL, bias, UWuOut, UWwOut, n0, wave, lane);
}

// ---------------- D5: final edge-max, 1024 blocks, 1 node/wave (TLP) ----------------
__global__ __launch_bounds__(256) void k_last(const unsigned short* __restrict__ UWuIn,
                                              const float* __restrict__ UWwIn,
                                              const int* __restrict__ cnt,
                                              const int* __restrict__ srcS,
                                              float* __restrict__ out, int ooff) {
    const int t = threadIdx.x, wave = t >> 6, lane = t & 63;
    const int i = blockIdx.x * 4 + wave;
    int deg = cnt[i]; deg = deg > 64 ? 64 : deg;
    const int base = i * 64;
    const float NEG = -3.4e38f;
    float m0 = NEG, m1 = NEG, m2 = NEG, m3 = NEG;
    int e = 0;
    for (; e + 4 <= deg; e += 4) {
        int s0 = srcS[base + e],     s1 = srcS[base + e + 1];
        int s2 = srcS[base + e + 2], s3 = srcS[base + e + 3];
        ushort4 v0 = *(const ushort4*)(UWuIn + (size_t)s0 * 256 + lane * 4);
        ushort4 v1 = *(const ushort4*)(UWuIn + (size_t)s1 * 256 + lane * 4);
        ushort4 v2 = *(const ushort4*)(UWuIn + (size_t)s2 * 256 + lane * 4);
        ushort4 v3 = *(const ushort4*)(UWuIn + (size_t)s3 * 256 + lane * 4);
        m0 = fmaxf(fmaxf(fmaxf(m0, bf2f(v0.x)), fmaxf(bf2f(v1.x), bf2f(v2.x))), bf2f(v3.x));
        m1 = fmaxf(fmaxf(fmaxf(m1, bf2f(v0.y)), fmaxf(bf2f(v1.y), bf2f(v2.y))), bf2f(v3.y));
        m2 = fmaxf(fmaxf(fmaxf(m2, bf2f(v0.z)), fmaxf(bf2f(v1.z), bf2f(v2.z))), bf2f(v3.z));
        m3 = fmaxf(fmaxf(fmaxf(m3, bf2f(v0.w)), fmaxf(bf2f(v1.w), bf2f(v2.w))), bf2f(v3.w));
    }
    for (; e < deg; ++e) {
        int s = srcS[base + e];
        ushort4 v = *(const ushort4*)(UWuIn + (size_t)s * 256 + lane * 4);
        m0 = fmaxf(m0, bf2f(v.x)); m1 = fmaxf(m1, bf2f(v.y));
        m2 = fmaxf(m2, bf2f(v.z)); m3 = fmaxf(m3, bf2f(v.w));
    }
    float4 w = *(const float4*)(UWwIn + (size_t)i * 256 + lane * 4);
    float4 r;
    r.x = fmaxf(m0 + w.x, 0.0f);
    r.y = fmaxf(m1 + w.y, 0.0f);
    r.z = fmaxf(m2 + w.z, 0.0f);
    r.w = fmaxf(m3 + w.w, 0.0f);
    *(float4*)(out + (size_t)i * OSTR + ooff + lane * 4) = r;
}

extern "C" void kernel_launch(void* const* d_in, const int* in_sizes, int n_in,
                              void* d_out, int out_size, void* d_ws, size_t ws_size,
                              hipStream_t stream) {
    const float* x0 = (const float*)d_in[0];
    const int* ei = (const int*)d_in[1];
    const int* srcIdx = ei;          // edge_index[0]
    const int* dstIdx = ei + EDGES;  // edge_index[1]
    float* out = (float*)d_out;

    // ws layout (~13.8 MB): UWuA 2M | UWwA 4M | UWuB 2M | UWwB 4M | Wp 768K | cnt 16K | srcS 1M
    char* w = (char*)d_ws;
    unsigned short* UWuA = (unsigned short*)w;
    float*          UWwA = (float*)(w + 2097152);
    unsigned short* UWuB = (unsigned short*)(w + 6291456);
    float*          UWwB = (float*)(w + 8388608);
    short*          Wp   = (short*)(w + 12582912);
    int*            cnt  = (int*)(w + 13369344);
    int*            srcS = (int*)(w + 13385728);

    k_setup<<<528, 256, 0, stream>>>((const float*)d_in[2], Wp, cnt);
    k_g0<<<1536, 256, 0, stream>>>(x0, Wp, (const float*)d_in[3], UWuA, UWwA,
                                   srcIdx, dstIdx, cnt, srcS,
                                   (const float*)d_in[4], (const float*)d_in[6], out);
    k_fuse<<<256, 256, 0, stream>>>(UWuA, UWwA, UWuB, UWwB, cnt, srcS,
                                    Wp + 131072, (const float*)d_in[5], out, 256);
    k_fuse<<<256, 256, 0, stream>>>(UWuB, UWwB, UWuA, UWwA, cnt, srcS,
                                    Wp + 262144, (const float*)d_in[7], out, 512);
    k_last<<<1024, 256, 0, stream>>>(UWuA, UWwA, cnt, srcS, out, 768);
}